// Round 19
// baseline (123.143 us; speedup 1.0000x reference)
//
#include <hip/hip_runtime.h>
#include <stdint.h>

typedef __attribute__((ext_vector_type(8))) short v8s;
typedef __attribute__((ext_vector_type(4))) short v4s;
typedef __attribute__((ext_vector_type(4))) float v4f;
typedef __attribute__((ext_vector_type(2))) unsigned v2u;
typedef unsigned short u16;

#define EMB 1024
#define TOKS 4096
#define NSEQ 2048
#define NH 16
#define HD 64

__device__ __forceinline__ u16 f2bf(float f) {
    unsigned u = __builtin_bit_cast(unsigned, f);
    u += 0x7fffu + ((u >> 16) & 1u);
    return (u16)(u >> 16);
}
__device__ __forceinline__ float bf2f(u16 h) {
    unsigned u = ((unsigned)h) << 16;
    return __builtin_bit_cast(float, u);
}
__device__ __forceinline__ float exp2_fast(float x) {
#if __has_builtin(__builtin_amdgcn_exp2f)
    return __builtin_amdgcn_exp2f(x);   // compiler-managed v_exp_f32 (trans hazards handled)
#else
    return exp2f(x);
#endif
}
// pack hi16(t0) -> low half, hi16(t1) -> high half (builtin perm; NO inline asm in exp chains)
__device__ __forceinline__ unsigned pack_hi16(unsigned t0, unsigned t1) {
#if __has_builtin(__builtin_amdgcn_perm)
    return __builtin_amdgcn_perm(t1, t0, 0x07060302u);  // [t1.b3,t1.b2,t0.b3,t0.b2]
#else
    return (t0 >> 16) | (t1 & 0xffff0000u);
#endif
}

__device__ __forceinline__ void gll16(const void* g, void* l) {
    __builtin_amdgcn_global_load_lds(
        (const __attribute__((address_space(1))) unsigned int*)g,
        (__attribute__((address_space(3))) unsigned int*)l, 16, 0, 0);
}

// ---------------- convert x -> bf16 hi-only [tok][1024] ----------------
__global__ void k_convx(const float* __restrict__ x, u16* __restrict__ xhi) {
    int i = (blockIdx.x * 256 + threadIdx.x) * 4;
    v4f v = *(const v4f*)(x + i);
    v4s h;
#pragma unroll
    for (int j = 0; j < 4; j++) h[j] = (short)f2bf(v[j]);
    *(v4s*)(xhi + i) = h;
}

// ---------------- transpose weights -> whi [z][out][1024] bf16 (all four) ----------------
__global__ void k_convw(const float* __restrict__ w0, const float* __restrict__ w1,
                        const float* __restrict__ w2, const float* __restrict__ w3,
                        u16* __restrict__ whi) {
    __shared__ float t[64][65];
    int z = blockIdx.z;
    const float* w = (z == 0) ? w0 : (z == 1) ? w1 : (z == 2) ? w2 : w3;
    int r0 = blockIdx.x * 64, c0 = blockIdx.y * 64;
    int tr = threadIdx.x >> 4, tc = (threadIdx.x & 15) * 4;
#pragma unroll
    for (int i = 0; i < 4; i++) {
        int row = tr + i * 16;
        v4f v = *(const v4f*)(w + (size_t)(r0 + row) * EMB + c0 + tc);
#pragma unroll
        for (int j = 0; j < 4; j++) t[row][tc + j] = v[j];
    }
    __syncthreads();
    u16* dz = whi + (size_t)z * EMB * EMB;
#pragma unroll
    for (int i = 0; i < 4; i++) {
        int orow = tr + i * 16;
        v4s h;
#pragma unroll
        for (int j = 0; j < 4; j++) h[j] = (short)f2bf(t[tc + j][orow]);
        *(v4s*)(dz + (size_t)(c0 + orow) * EMB + r0 + tc) = h;
    }
}

// ---------------- plain-bf16 GEMM K=1024 (m97 schedule): QKV projections ----------------
__global__ __launch_bounds__(256, 2) void k_gemm(
    const u16* __restrict__ A, const u16* __restrict__ B0,
    const float* __restrict__ b0, const float* __restrict__ b1, const float* __restrict__ b2,
    u16* __restrict__ outBF, u16* __restrict__ vT) {
    __shared__ u16 sA[8192], sB[8192];
    int z = blockIdx.z;
    const u16* B = B0 + (size_t)z * EMB * EMB;
    const float* bias = (z == 0) ? b0 : (z == 1) ? b1 : b2;
    int f = blockIdx.y * 32 + blockIdx.x;
    int fp = (f & 7) * 32 + (f >> 3);
    int m0 = (fp & 31) * 128, n0 = (fp >> 5) * 128;
    int tid = threadIdx.x, lane = tid & 63, w = tid >> 6;
    int wm = w >> 1, wn = w & 1;
    int lr = lane & 15, lk = lane >> 4;
    int srow8 = lane >> 3, kc8 = lane & 7;
    v4f z4 = {0.f, 0.f, 0.f, 0.f};
    v4f acc[4][4];
#pragma unroll
    for (int mi = 0; mi < 4; mi++)
#pragma unroll
        for (int ni = 0; ni < 4; ni++) acc[mi][ni] = z4;

    int c0 = (lk ^ (lr & 7)) * 8, c1 = ((4 + lk) ^ (lr & 7)) * 8;
    for (int kt = 0; kt < 16; ++kt) {
#pragma unroll
        for (int ii = 0; ii < 4; ii++) {
            int it = w * 4 + ii;
            int row = it * 8 + srow8;
            int kc = kc8 ^ (row & 7);
            gll16(&A[(size_t)(m0 + row) * EMB + kt * 64 + kc * 8], &sA[it * 512]);
            gll16(&B[(size_t)(n0 + row) * EMB + kt * 64 + kc * 8], &sB[it * 512]);
        }
        __syncthreads();
        v8s af[4][2], bf[4][2];
#pragma unroll
        for (int i = 0; i < 4; i++) {
            int ra = (wm * 64 + i * 16 + lr) * 64;
            af[i][0] = *(const v8s*)(&sA[ra + c0]);
            af[i][1] = *(const v8s*)(&sA[ra + c1]);
            int rb = (wn * 64 + i * 16 + lr) * 64;
            bf[i][0] = *(const v8s*)(&sB[rb + c0]);
            bf[i][1] = *(const v8s*)(&sB[rb + c1]);
        }
#pragma unroll
        for (int mi = 0; mi < 4; mi++)
#pragma unroll
            for (int ni = 0; ni < 4; ni++) {
                acc[mi][ni] = __builtin_amdgcn_mfma_f32_16x16x32_bf16(af[mi][0], bf[ni][0], acc[mi][ni], 0, 0, 0);
                acc[mi][ni] = __builtin_amdgcn_mfma_f32_16x16x32_bf16(af[mi][1], bf[ni][1], acc[mi][ni], 0, 0, 0);
            }
        __syncthreads();
    }

#pragma unroll
    for (int mi = 0; mi < 4; mi++) {
#pragma unroll
        for (int ni = 0; ni < 4; ni++) {
            int col = n0 + wn * 64 + ni * 16 + lr;
            float bv = bias[col];
            if (z == 2) {
                int h = col >> 6, d = col & 63;
                v4s pk;
#pragma unroll
                for (int r = 0; r < 4; r++) pk[r] = (short)f2bf(acc[mi][ni][r] + bv);
                int row = m0 + wm * 64 + mi * 16 + lk * 4;
                int bb = row >> 11, nn = row & 2047;
                *(v4s*)(&vT[((size_t)(bb * NH + h) * HD + d) * NSEQ + nn]) = pk;
            } else {
#pragma unroll
                for (int r = 0; r < 4; r++) {
                    int row = m0 + wm * 64 + mi * 16 + lk * 4 + r;
                    float val = acc[mi][ni][r] + bv;
                    if (z == 0) val *= 0.18033688011112042f;  // (1/8)*log2(e)
                    int bb = row >> 11, nn = row & 2047, h = col >> 6, d = col & 63;
                    size_t idx = (((size_t)(bb * NH + h)) * NSEQ + nn) * HD + d;
                    (outBF + (size_t)z * TOKS * EMB)[idx] = f2bf(val);
                }
            }
        }
    }
}

// ---------------- O-projection: 64x128 tile, K=1024 plain-bf16 (grid 512 = 2 blocks/CU) ----------------
__global__ __launch_bounds__(256, 2) void k_gemmO(
    const u16* __restrict__ A, const u16* __restrict__ B,
    const float* __restrict__ bias, float* __restrict__ outF) {
    __shared__ u16 sA[4096], sB[8192];
    int f = blockIdx.y * 64 + blockIdx.x;
    int fp = (f & 7) * 64 + (f >> 3);
    int m0 = (fp & 63) * 64, n0 = (fp >> 6) * 128;
    int tid = threadIdx.x, lane = tid & 63, w = tid >> 6;
    int wm = w >> 1, wn = w & 1;
    int lr = lane & 15, lk = lane >> 4;
    int srow8 = lane >> 3, kc8 = lane & 7;
    v4f z4 = {0.f, 0.f, 0.f, 0.f};
    v4f acc[2][4];
#pragma unroll
    for (int mi = 0; mi < 2; mi++)
#pragma unroll
        for (int ni = 0; ni < 4; ni++) acc[mi][ni] = z4;

    int c0 = (lk ^ (lr & 7)) * 8, c1 = ((4 + lk) ^ (lr & 7)) * 8;
    for (int kt = 0; kt < 16; ++kt) {
#pragma unroll
        for (int ii = 0; ii < 2; ii++) {
            int it = w * 2 + ii;
            int row = it * 8 + srow8;
            int kc = kc8 ^ (row & 7);
            gll16(&A[(size_t)(m0 + row) * EMB + kt * 64 + kc * 8], &sA[it * 512]);
        }
#pragma unroll
        for (int ii = 0; ii < 4; ii++) {
            int it = w * 4 + ii;
            int row = it * 8 + srow8;
            int kc = kc8 ^ (row & 7);
            gll16(&B[(size_t)(n0 + row) * EMB + kt * 64 + kc * 8], &sB[it * 512]);
        }
        __syncthreads();
        v8s af[2][2], bf[4][2];
#pragma unroll
        for (int i = 0; i < 2; i++) {
            int ra = (wm * 32 + i * 16 + lr) * 64;
            af[i][0] = *(const v8s*)(&sA[ra + c0]);
            af[i][1] = *(const v8s*)(&sA[ra + c1]);
        }
#pragma unroll
        for (int i = 0; i < 4; i++) {
            int rb = (wn * 64 + i * 16 + lr) * 64;
            bf[i][0] = *(const v8s*)(&sB[rb + c0]);
            bf[i][1] = *(const v8s*)(&sB[rb + c1]);
        }
#pragma unroll
        for (int mi = 0; mi < 2; mi++)
#pragma unroll
            for (int ni = 0; ni < 4; ni++) {
                acc[mi][ni] = __builtin_amdgcn_mfma_f32_16x16x32_bf16(af[mi][0], bf[ni][0], acc[mi][ni], 0, 0, 0);
                acc[mi][ni] = __builtin_amdgcn_mfma_f32_16x16x32_bf16(af[mi][1], bf[ni][1], acc[mi][ni], 0, 0, 0);
            }
        __syncthreads();
    }
#pragma unroll
    for (int mi = 0; mi < 2; mi++)
#pragma unroll
        for (int ni = 0; ni < 4; ni++) {
            int col = n0 + wn * 64 + ni * 16 + lr;
            float bv = bias[col];
#pragma unroll
            for (int r = 0; r < 4; r++) {
                int row = m0 + wm * 32 + mi * 16 + lk * 4 + r;
                outF[(size_t)row * EMB + col] = acc[mi][ni][r] + bv;
            }
        }
}

// ---------------- flash attention, 2-way KV-split: partial O (bf16) + partial l (f32) ----------------
// Grid 2048: bid -> {XCD-friendly bh low bits, kv-half, qi, bh high bits}. 16 tiles per block.
// No-max softmax => partials combine exactly: O = (O1+O2)/(l1+l2).
__global__ __launch_bounds__(256, 4) void k_attn(
    const u16* __restrict__ Q, const u16* __restrict__ K, const u16* __restrict__ Vt,
    u16* __restrict__ Opart, float* __restrict__ Lpart) {
    __shared__ u16 sK[2][4096];
    __shared__ u16 sP[4096];
    float* sL = (float*)&sK[0][0];   // alias: all sK reads precede the final in-loop barrier
    int tid = threadIdx.x, lane = tid & 63, w = tid >> 6;
    int lr = lane & 15, lk = lane >> 4;
    int bid = blockIdx.x;
    int kvh = (bid >> 3) & 1;
    int qi = (bid >> 4) & 31;
    int bh = (bid & 7) | (((bid >> 9) & 3) << 3);  // bid%8 = XCD slot; 4 bh/XCD L2-resident
    int q0 = qi * 64;
    int t0 = kvh * 16;   // even -> cur parity starts at 0 for both halves

    const u16* Qb = Q + ((size_t)bh * NSEQ + q0) * HD;
    v8s qf[4][2];
#pragma unroll
    for (int qg = 0; qg < 4; qg++)
#pragma unroll
        for (int c = 0; c < 2; c++)
            qf[qg][c] = *(const v8s*)(Qb + (qg * 16 + lr) * HD + c * 32 + lk * 8);

    const u16* Kb = K + (size_t)bh * NSEQ * HD;
    const u16* Vb = Vt + ((size_t)bh * HD + w * 16 + lr) * NSEQ;
    v4f z4 = {0.f, 0.f, 0.f, 0.f};
    v4f oacc[4] = {z4, z4, z4, z4};
    float l_part[4] = {0.f, 0.f, 0.f, 0.f};
    int srow8 = lane >> 3, kc8 = lane & 7;

    // prologue: stage K tile t0
#pragma unroll
    for (int ii = 0; ii < 2; ii++) {
        int it = w * 2 + ii;
        int row = it * 8 + srow8;
        int kc = kc8 ^ (row & 7);
        gll16(&Kb[(size_t)(t0 * 64 + row) * HD + kc * 8], &sK[0][it * 512]);
    }
    __syncthreads();

    int kread0 = (w * 16 + lr) * 64 + ((lk ^ (lr & 7)) * 8);
    int kread1 = (w * 16 + lr) * 64 + (((4 + lk) ^ (lr & 7)) * 8);
    int pwbase = (((w * 2 + (lk >> 1)) ^ (lr & 7)) << 2) + (lk & 1) * 2;

    for (int t = t0; t < t0 + 16; ++t) {
        int cur = t & 1;
        if (t < t0 + 15) {
#pragma unroll
            for (int ii = 0; ii < 2; ii++) {
                int it = w * 2 + ii;
                int row = it * 8 + srow8;
                int kc = kc8 ^ (row & 7);
                gll16(&Kb[(size_t)((t + 1) * 64 + row) * HD + kc * 8], &sK[cur ^ 1][it * 512]);
            }
        }
        v8s vb0 = *(const v8s*)(Vb + t * 64 + lk * 8);
        v8s vb1 = *(const v8s*)(Vb + t * 64 + 32 + lk * 8);

        v8s kf0 = *(const v8s*)(&sK[cur][kread0]);
        v8s kf1 = *(const v8s*)(&sK[cur][kread1]);
        v4f sacc[4];
#pragma unroll
        for (int qg = 0; qg < 4; qg++) {
            v4f a = z4;
            a = __builtin_amdgcn_mfma_f32_16x16x32_bf16(kf0, qf[qg][0], a, 0, 0, 0);
            a = __builtin_amdgcn_mfma_f32_16x16x32_bf16(kf1, qf[qg][1], a, 0, 0, 0);
            sacc[qg] = a;
        }
        float pv[4][4];
#pragma unroll
        for (int qg = 0; qg < 4; qg++) {
            pv[qg][0] = exp2_fast(sacc[qg][0]);
            pv[qg][1] = exp2_fast(sacc[qg][1]);
            pv[qg][2] = exp2_fast(sacc[qg][2]);
            pv[qg][3] = exp2_fast(sacc[qg][3]);
            l_part[qg] += (pv[qg][0] + pv[qg][1]) + (pv[qg][2] + pv[qg][3]);
        }
        __syncthreads();   // barrier A: prev tile's sP readers done
#pragma unroll
        for (int qg = 0; qg < 4; qg++) {
            unsigned pk0 = pack_hi16(__builtin_bit_cast(unsigned, pv[qg][0]),
                                     __builtin_bit_cast(unsigned, pv[qg][1]));
            unsigned pk1 = pack_hi16(__builtin_bit_cast(unsigned, pv[qg][2]),
                                     __builtin_bit_cast(unsigned, pv[qg][3]));
            int q = qg * 16 + lr;
            v2u pk = {pk0, pk1};
            *(v2u*)(&sP[(q * 32 + pwbase) * 2]) = pk;
        }
        __syncthreads();   // barrier B: sP visible; gll16 of next tile drained
#pragma unroll
        for (int qg = 0; qg < 4; qg++) {
            int q = qg * 16 + lr;
            v8s pf0 = *(const v8s*)(&sP[(q * 32 + ((lk ^ (lr & 7)) << 2)) * 2]);
            v8s pf1 = *(const v8s*)(&sP[(q * 32 + (((4 + lk) ^ (lr & 7)) << 2)) * 2]);
            oacc[qg] = __builtin_amdgcn_mfma_f32_16x16x32_bf16(pf0, vb0, oacc[qg], 0, 0, 0);
            oacc[qg] = __builtin_amdgcn_mfma_f32_16x16x32_bf16(pf1, vb1, oacc[qg], 0, 0, 0);
        }
    }
    // deferred l: reduce across lk, then across waves via sL (aliased over dead sK)
#pragma unroll
    for (int qg = 0; qg < 4; qg++) {
        l_part[qg] += __shfl_xor(l_part[qg], 16);
        l_part[qg] += __shfl_xor(l_part[qg], 32);
    }
    __syncthreads();
    if (lk == 0) {
#pragma unroll
        for (int qg = 0; qg < 4; qg++) sL[(qg * 16 + lr) * 4 + w] = l_part[qg];
    }
    __syncthreads();
    int bb = bh >> 4, h = bh & 15;
    int dcol = h * 64 + w * 16 + lr;
    u16* Op = Opart + (size_t)kvh * TOKS * EMB;
    float* Lp = Lpart + (size_t)kvh * 32 * NSEQ + (size_t)bh * NSEQ;
#pragma unroll
    for (int qg = 0; qg < 4; qg++) {
#pragma unroll
        for (int r = 0; r < 4; r++) {
            int qq = qg * 16 + lk * 4 + r;
            Op[(size_t)(bb * NSEQ + q0 + qq) * EMB + dcol] = f2bf(oacc[qg][r]);
            if (w == 0 && lr == 0) {
                v4f lv = *(const v4f*)(&sL[qq * 4]);
                Lp[q0 + qq] = (lv[0] + lv[1]) + (lv[2] + lv[3]);
            }
        }
    }
}

// ---------------- combine: O = (O1 + O2) / (l1 + l2) ----------------
__global__ void k_comb(const u16* __restrict__ Opart, const float* __restrict__ Lpart,
                       u16* __restrict__ O) {
    int i = (blockIdx.x * 256 + threadIdx.x) * 4;
    int tok = i >> 10, col = i & 1023;
    int bb = tok >> 11, nn = tok & 2047, h = col >> 6;
    int bhi = bb * NH + h;
    float inv = 1.f / (Lpart[(size_t)bhi * NSEQ + nn] +
                       Lpart[(size_t)32 * NSEQ + (size_t)bhi * NSEQ + nn]);
    v4s a = *(const v4s*)(Opart + i);
    v4s b = *(const v4s*)(Opart + (size_t)TOKS * EMB + i);
    v4s o;
#pragma unroll
    for (int j = 0; j < 4; j++)
        o[j] = (short)f2bf((bf2f((u16)a[j]) + bf2f((u16)b[j])) * inv);
    *(v4s*)(O + i) = o;
}

extern "C" void kernel_launch(void* const* d_in, const int* in_sizes, int n_in,
                              void* d_out, int out_size, void* d_ws, size_t ws_size,
                              hipStream_t stream) {
    const float* x  = (const float*)d_in[0];
    const float* wq = (const float*)d_in[1];
    const float* bq = (const float*)d_in[2];
    const float* wk = (const float*)d_in[3];
    const float* bk = (const float*)d_in[4];
    const float* wv = (const float*)d_in[5];
    const float* bv = (const float*)d_in[6];
    const float* wo = (const float*)d_in[7];
    const float* bo = (const float*)d_in[8];

    char* W = (char*)d_ws;
    u16* xhi   = (u16*)(W);                 // [4096][1024]            8 MB
    u16* whi   = (u16*)(W + 8388608);       // [4][1024][1024]         8 MB
    u16* qkv   = (u16*)(W + 16777216);      // Q,K [32][2048][64]; V^T [32][64][2048]  24 MB
    u16* Obf   = (u16*)(W + 41943040);      // [4096][1024] bf16       8 MB
    u16* Opart = (u16*)(W + 50331648);      // 2 x [4096][1024] bf16  16 MB
    float* Lpart = (float*)(W + 67108864);  // 2 x [32][2048] f32    0.5 MB

    u16* Qp  = qkv;
    u16* Kp  = qkv + 4194304;
    u16* Vtp = qkv + 8388608;

    k_convx<<<4096, 256, 0, stream>>>(x, xhi);
    k_convw<<<dim3(16, 16, 4), 256, 0, stream>>>(wq, wk, wv, wo, whi);
    k_gemm<<<dim3(32, 8, 3), 256, 0, stream>>>(xhi, whi, bq, bk, bv, qkv, Vtp);
    k_attn<<<dim3(2048), 256, 0, stream>>>(Qp, Kp, Vtp, Opart, Lpart);
    k_comb<<<4096, 256, 0, stream>>>(Opart, Lpart, Obf);
    k_gemmO<<<dim3(64, 8), 256, 0, stream>>>(Obf, whi + (size_t)3 * EMB * EMB,
                                             bo, (float*)d_out);
}

// Round 20
// 115.344 us; speedup vs baseline: 1.0676x; 1.0676x over previous
//
#include <hip/hip_runtime.h>
#include <stdint.h>

typedef __attribute__((ext_vector_type(8))) short v8s;
typedef __attribute__((ext_vector_type(4))) short v4s;
typedef __attribute__((ext_vector_type(4))) float v4f;
typedef __attribute__((ext_vector_type(2))) unsigned v2u;
typedef unsigned short u16;

#define EMB 1024
#define TOKS 4096
#define NSEQ 2048
#define NH 16
#define HD 64

__device__ __forceinline__ u16 f2bf(float f) {
    unsigned u = __builtin_bit_cast(unsigned, f);
    u += 0x7fffu + ((u >> 16) & 1u);
    return (u16)(u >> 16);
}
__device__ __forceinline__ float bf2f(u16 h) {
    unsigned u = ((unsigned)h) << 16;
    return __builtin_bit_cast(float, u);
}
__device__ __forceinline__ float exp2_fast(float x) {
#if __has_builtin(__builtin_amdgcn_exp2f)
    return __builtin_amdgcn_exp2f(x);   // compiler-managed v_exp_f32 (trans hazards handled)
#else
    return exp2f(x);
#endif
}
// pack hi16(t0) -> low half, hi16(t1) -> high half (builtin perm; NO inline asm in exp chains)
__device__ __forceinline__ unsigned pack_hi16(unsigned t0, unsigned t1) {
#if __has_builtin(__builtin_amdgcn_perm)
    return __builtin_amdgcn_perm(t1, t0, 0x07060302u);  // [t1.b3,t1.b2,t0.b3,t0.b2]
#else
    return (t0 >> 16) | (t1 & 0xffff0000u);
#endif
}

__device__ __forceinline__ void gll16(const void* g, void* l) {
    __builtin_amdgcn_global_load_lds(
        (const __attribute__((address_space(1))) unsigned int*)g,
        (__attribute__((address_space(3))) unsigned int*)l, 16, 0, 0);
}

// ---------------- convert x -> bf16 hi-only [tok][1024] ----------------
__global__ void k_convx(const float* __restrict__ x, u16* __restrict__ xhi) {
    int i = (blockIdx.x * 256 + threadIdx.x) * 4;
    v4f v = *(const v4f*)(x + i);
    v4s h;
#pragma unroll
    for (int j = 0; j < 4; j++) h[j] = (short)f2bf(v[j]);
    *(v4s*)(xhi + i) = h;
}

// ---------------- transpose weights -> whi [z][out][1024] bf16 (all four) ----------------
__global__ void k_convw(const float* __restrict__ w0, const float* __restrict__ w1,
                        const float* __restrict__ w2, const float* __restrict__ w3,
                        u16* __restrict__ whi) {
    __shared__ float t[64][65];
    int z = blockIdx.z;
    const float* w = (z == 0) ? w0 : (z == 1) ? w1 : (z == 2) ? w2 : w3;
    int r0 = blockIdx.x * 64, c0 = blockIdx.y * 64;
    int tr = threadIdx.x >> 4, tc = (threadIdx.x & 15) * 4;
#pragma unroll
    for (int i = 0; i < 4; i++) {
        int row = tr + i * 16;
        v4f v = *(const v4f*)(w + (size_t)(r0 + row) * EMB + c0 + tc);
#pragma unroll
        for (int j = 0; j < 4; j++) t[row][tc + j] = v[j];
    }
    __syncthreads();
    u16* dz = whi + (size_t)z * EMB * EMB;
#pragma unroll
    for (int i = 0; i < 4; i++) {
        int orow = tr + i * 16;
        v4s h;
#pragma unroll
        for (int j = 0; j < 4; j++) h[j] = (short)f2bf(t[tc + j][orow]);
        *(v4s*)(dz + (size_t)(c0 + orow) * EMB + r0 + tc) = h;
    }
}

// ---------------- plain-bf16 GEMM K=1024 (m97 schedule): QKV projections ----------------
__global__ __launch_bounds__(256, 2) void k_gemm(
    const u16* __restrict__ A, const u16* __restrict__ B0,
    const float* __restrict__ b0, const float* __restrict__ b1, const float* __restrict__ b2,
    u16* __restrict__ outBF, u16* __restrict__ vT) {
    __shared__ u16 sA[8192], sB[8192];
    int z = blockIdx.z;
    const u16* B = B0 + (size_t)z * EMB * EMB;
    const float* bias = (z == 0) ? b0 : (z == 1) ? b1 : b2;
    int f = blockIdx.y * 32 + blockIdx.x;
    int fp = (f & 7) * 32 + (f >> 3);
    int m0 = (fp & 31) * 128, n0 = (fp >> 5) * 128;
    int tid = threadIdx.x, lane = tid & 63, w = tid >> 6;
    int wm = w >> 1, wn = w & 1;
    int lr = lane & 15, lk = lane >> 4;
    int srow8 = lane >> 3, kc8 = lane & 7;
    v4f z4 = {0.f, 0.f, 0.f, 0.f};
    v4f acc[4][4];
#pragma unroll
    for (int mi = 0; mi < 4; mi++)
#pragma unroll
        for (int ni = 0; ni < 4; ni++) acc[mi][ni] = z4;

    int c0 = (lk ^ (lr & 7)) * 8, c1 = ((4 + lk) ^ (lr & 7)) * 8;
    for (int kt = 0; kt < 16; ++kt) {
#pragma unroll
        for (int ii = 0; ii < 4; ii++) {
            int it = w * 4 + ii;
            int row = it * 8 + srow8;
            int kc = kc8 ^ (row & 7);
            gll16(&A[(size_t)(m0 + row) * EMB + kt * 64 + kc * 8], &sA[it * 512]);
            gll16(&B[(size_t)(n0 + row) * EMB + kt * 64 + kc * 8], &sB[it * 512]);
        }
        __syncthreads();
        v8s af[4][2], bf[4][2];
#pragma unroll
        for (int i = 0; i < 4; i++) {
            int ra = (wm * 64 + i * 16 + lr) * 64;
            af[i][0] = *(const v8s*)(&sA[ra + c0]);
            af[i][1] = *(const v8s*)(&sA[ra + c1]);
            int rb = (wn * 64 + i * 16 + lr) * 64;
            bf[i][0] = *(const v8s*)(&sB[rb + c0]);
            bf[i][1] = *(const v8s*)(&sB[rb + c1]);
        }
#pragma unroll
        for (int mi = 0; mi < 4; mi++)
#pragma unroll
            for (int ni = 0; ni < 4; ni++) {
                acc[mi][ni] = __builtin_amdgcn_mfma_f32_16x16x32_bf16(af[mi][0], bf[ni][0], acc[mi][ni], 0, 0, 0);
                acc[mi][ni] = __builtin_amdgcn_mfma_f32_16x16x32_bf16(af[mi][1], bf[ni][1], acc[mi][ni], 0, 0, 0);
            }
        __syncthreads();
    }

#pragma unroll
    for (int mi = 0; mi < 4; mi++) {
#pragma unroll
        for (int ni = 0; ni < 4; ni++) {
            int col = n0 + wn * 64 + ni * 16 + lr;
            float bv = bias[col];
            if (z == 2) {
                int h = col >> 6, d = col & 63;
                v4s pk;
#pragma unroll
                for (int r = 0; r < 4; r++) pk[r] = (short)f2bf(acc[mi][ni][r] + bv);
                int row = m0 + wm * 64 + mi * 16 + lk * 4;
                int bb = row >> 11, nn = row & 2047;
                *(v4s*)(&vT[((size_t)(bb * NH + h) * HD + d) * NSEQ + nn]) = pk;
            } else {
#pragma unroll
                for (int r = 0; r < 4; r++) {
                    int row = m0 + wm * 64 + mi * 16 + lk * 4 + r;
                    float val = acc[mi][ni][r] + bv;
                    if (z == 0) val *= 0.18033688011112042f;  // (1/8)*log2(e)
                    int bb = row >> 11, nn = row & 2047, h = col >> 6, d = col & 63;
                    size_t idx = (((size_t)(bb * NH + h)) * NSEQ + nn) * HD + d;
                    (outBF + (size_t)z * TOKS * EMB)[idx] = f2bf(val);
                }
            }
        }
    }
}

// ---------------- O-projection: 64x128 tile, K=1024 plain-bf16 (grid 512 = 2 blocks/CU) ----------------
__global__ __launch_bounds__(256, 2) void k_gemmO(
    const u16* __restrict__ A, const u16* __restrict__ B,
    const float* __restrict__ bias, float* __restrict__ outF) {
    __shared__ u16 sA[4096], sB[8192];
    int f = blockIdx.y * 64 + blockIdx.x;
    int fp = (f & 7) * 64 + (f >> 3);
    int m0 = (fp & 63) * 64, n0 = (fp >> 6) * 128;
    int tid = threadIdx.x, lane = tid & 63, w = tid >> 6;
    int wm = w >> 1, wn = w & 1;
    int lr = lane & 15, lk = lane >> 4;
    int srow8 = lane >> 3, kc8 = lane & 7;
    v4f z4 = {0.f, 0.f, 0.f, 0.f};
    v4f acc[2][4];
#pragma unroll
    for (int mi = 0; mi < 2; mi++)
#pragma unroll
        for (int ni = 0; ni < 4; ni++) acc[mi][ni] = z4;

    int c0 = (lk ^ (lr & 7)) * 8, c1 = ((4 + lk) ^ (lr & 7)) * 8;
    for (int kt = 0; kt < 16; ++kt) {
#pragma unroll
        for (int ii = 0; ii < 2; ii++) {
            int it = w * 2 + ii;
            int row = it * 8 + srow8;
            int kc = kc8 ^ (row & 7);
            gll16(&A[(size_t)(m0 + row) * EMB + kt * 64 + kc * 8], &sA[it * 512]);
        }
#pragma unroll
        for (int ii = 0; ii < 4; ii++) {
            int it = w * 4 + ii;
            int row = it * 8 + srow8;
            int kc = kc8 ^ (row & 7);
            gll16(&B[(size_t)(n0 + row) * EMB + kt * 64 + kc * 8], &sB[it * 512]);
        }
        __syncthreads();
        v8s af[2][2], bf[4][2];
#pragma unroll
        for (int i = 0; i < 2; i++) {
            int ra = (wm * 32 + i * 16 + lr) * 64;
            af[i][0] = *(const v8s*)(&sA[ra + c0]);
            af[i][1] = *(const v8s*)(&sA[ra + c1]);
        }
#pragma unroll
        for (int i = 0; i < 4; i++) {
            int rb = (wn * 64 + i * 16 + lr) * 64;
            bf[i][0] = *(const v8s*)(&sB[rb + c0]);
            bf[i][1] = *(const v8s*)(&sB[rb + c1]);
        }
#pragma unroll
        for (int mi = 0; mi < 2; mi++)
#pragma unroll
            for (int ni = 0; ni < 4; ni++) {
                acc[mi][ni] = __builtin_amdgcn_mfma_f32_16x16x32_bf16(af[mi][0], bf[ni][0], acc[mi][ni], 0, 0, 0);
                acc[mi][ni] = __builtin_amdgcn_mfma_f32_16x16x32_bf16(af[mi][1], bf[ni][1], acc[mi][ni], 0, 0, 0);
            }
        __syncthreads();
    }
#pragma unroll
    for (int mi = 0; mi < 2; mi++)
#pragma unroll
        for (int ni = 0; ni < 4; ni++) {
            int col = n0 + wn * 64 + ni * 16 + lr;
            float bv = bias[col];
#pragma unroll
            for (int r = 0; r < 4; r++) {
                int row = m0 + wm * 32 + mi * 16 + lk * 4 + r;
                outF[(size_t)row * EMB + col] = acc[mi][ni][r] + bv;
            }
        }
}

// ---------------- flash attention (R18 structure + T5 setprio around MFMA clusters) ----------------
// 4 waves x 64 q-rows, 64-key tiles, k-split K reads, trunc pack, single sP + 2 barriers/tile.
// LDS 24KB. sL aliased over sK (dead after last in-loop barrier).
__global__ __launch_bounds__(256, 4) void k_attn(
    const u16* __restrict__ Q, const u16* __restrict__ K, const u16* __restrict__ Vt,
    u16* __restrict__ O) {
    __shared__ u16 sK[2][4096];
    __shared__ u16 sP[4096];
    float* sL = (float*)&sK[0][0];   // alias: all sK reads precede the final in-loop barrier
    int tid = threadIdx.x, lane = tid & 63, w = tid >> 6;
    int lr = lane & 15, lk = lane >> 4;
    int bid = blockIdx.x;
    int qi = (bid >> 3) & 31;
    int bh = (bid & 7) | (((bid >> 8) & 3) << 3);  // bid%8 = XCD; 4 bh/XCD -> K,Vt L2-resident
    int q0 = qi * 64;

    const u16* Qb = Q + ((size_t)bh * NSEQ + q0) * HD;
    v8s qf[4][2];
#pragma unroll
    for (int qg = 0; qg < 4; qg++)
#pragma unroll
        for (int c = 0; c < 2; c++)
            qf[qg][c] = *(const v8s*)(Qb + (qg * 16 + lr) * HD + c * 32 + lk * 8);

    const u16* Kb = K + (size_t)bh * NSEQ * HD;
    const u16* Vb = Vt + ((size_t)bh * HD + w * 16 + lr) * NSEQ;  // this wave's d-row
    v4f z4 = {0.f, 0.f, 0.f, 0.f};
    v4f oacc[4] = {z4, z4, z4, z4};
    float l_part[4] = {0.f, 0.f, 0.f, 0.f};
    int srow8 = lane >> 3, kc8 = lane & 7;

    // prologue: stage K tile 0
#pragma unroll
    for (int ii = 0; ii < 2; ii++) {
        int it = w * 2 + ii;
        int row = it * 8 + srow8;
        int kc = kc8 ^ (row & 7);
        gll16(&Kb[(size_t)row * HD + kc * 8], &sK[0][it * 512]);
    }
    __syncthreads();

    int kread0 = (w * 16 + lr) * 64 + ((lk ^ (lr & 7)) * 8);
    int kread1 = (w * 16 + lr) * 64 + (((4 + lk) ^ (lr & 7)) * 8);
    int pwbase = (((w * 2 + (lk >> 1)) ^ (lr & 7)) << 2) + (lk & 1) * 2;

    for (int t = 0; t < 32; ++t) {
        int cur = t & 1;
        if (t < 31) {
#pragma unroll
            for (int ii = 0; ii < 2; ii++) {
                int it = w * 2 + ii;
                int row = it * 8 + srow8;
                int kc = kc8 ^ (row & 7);
                gll16(&Kb[(size_t)((t + 1) * 64 + row) * HD + kc * 8], &sK[cur ^ 1][it * 512]);
            }
        }
        v8s vb0 = *(const v8s*)(Vb + t * 64 + lk * 8);
        v8s vb1 = *(const v8s*)(Vb + t * 64 + 32 + lk * 8);

        v8s kf0 = *(const v8s*)(&sK[cur][kread0]);
        v8s kf1 = *(const v8s*)(&sK[cur][kread1]);
        v4f sacc[4];
        __builtin_amdgcn_s_setprio(1);
#pragma unroll
        for (int qg = 0; qg < 4; qg++) {
            v4f a = z4;
            a = __builtin_amdgcn_mfma_f32_16x16x32_bf16(kf0, qf[qg][0], a, 0, 0, 0);
            a = __builtin_amdgcn_mfma_f32_16x16x32_bf16(kf1, qf[qg][1], a, 0, 0, 0);
            sacc[qg] = a;
        }
        __builtin_amdgcn_s_setprio(0);
        // p = exp2(s); f32 l accumulate; TRUNCATION pack (softmax ratio cancels the uniform bias)
        float pv[4][4];
#pragma unroll
        for (int qg = 0; qg < 4; qg++) {
            pv[qg][0] = exp2_fast(sacc[qg][0]);
            pv[qg][1] = exp2_fast(sacc[qg][1]);
            pv[qg][2] = exp2_fast(sacc[qg][2]);
            pv[qg][3] = exp2_fast(sacc[qg][3]);
            l_part[qg] += (pv[qg][0] + pv[qg][1]) + (pv[qg][2] + pv[qg][3]);
        }
        __syncthreads();   // barrier A: prev tile's sP readers are done
#pragma unroll
        for (int qg = 0; qg < 4; qg++) {
            unsigned pk0 = pack_hi16(__builtin_bit_cast(unsigned, pv[qg][0]),
                                     __builtin_bit_cast(unsigned, pv[qg][1]));
            unsigned pk1 = pack_hi16(__builtin_bit_cast(unsigned, pv[qg][2]),
                                     __builtin_bit_cast(unsigned, pv[qg][3]));
            int q = qg * 16 + lr;
            v2u pk = {pk0, pk1};
            *(v2u*)(&sP[(q * 32 + pwbase) * 2]) = pk;
        }
        __syncthreads();   // barrier B: sP visible; drains this tile's gll16 (sK[cur^1] ready)
        __builtin_amdgcn_s_setprio(1);
#pragma unroll
        for (int qg = 0; qg < 4; qg++) {
            int q = qg * 16 + lr;
            v8s pf0 = *(const v8s*)(&sP[(q * 32 + ((lk ^ (lr & 7)) << 2)) * 2]);
            v8s pf1 = *(const v8s*)(&sP[(q * 32 + (((4 + lk) ^ (lr & 7)) << 2)) * 2]);
            oacc[qg] = __builtin_amdgcn_mfma_f32_16x16x32_bf16(pf0, vb0, oacc[qg], 0, 0, 0);
            oacc[qg] = __builtin_amdgcn_mfma_f32_16x16x32_bf16(pf1, vb1, oacc[qg], 0, 0, 0);
        }
        __builtin_amdgcn_s_setprio(0);
    }
    // deferred l: reduce across lk groups, then across waves via sL (aliased over dead sK)
#pragma unroll
    for (int qg = 0; qg < 4; qg++) {
        l_part[qg] += __shfl_xor(l_part[qg], 16);
        l_part[qg] += __shfl_xor(l_part[qg], 32);
    }
    __syncthreads();   // all PV reads of sP done; sK fully dead -> safe to write sL alias
    if (lk == 0) {
#pragma unroll
        for (int qg = 0; qg < 4; qg++) sL[(qg * 16 + lr) * 4 + w] = l_part[qg];
    }
    __syncthreads();
    int bb = bh >> 4, h = bh & 15;
    int dcol = h * 64 + w * 16 + lr;
#pragma unroll
    for (int qg = 0; qg < 4; qg++) {
#pragma unroll
        for (int r = 0; r < 4; r++) {
            int qq = qg * 16 + lk * 4 + r;
            v4f lv = *(const v4f*)(&sL[qq * 4]);
            float inv = 1.f / ((lv[0] + lv[1]) + (lv[2] + lv[3]));
            O[(size_t)(bb * NSEQ + q0 + qq) * EMB + dcol] = f2bf(oacc[qg][r] * inv);
        }
    }
}

extern "C" void kernel_launch(void* const* d_in, const int* in_sizes, int n_in,
                              void* d_out, int out_size, void* d_ws, size_t ws_size,
                              hipStream_t stream) {
    const float* x  = (const float*)d_in[0];
    const float* wq = (const float*)d_in[1];
    const float* bq = (const float*)d_in[2];
    const float* wk = (const float*)d_in[3];
    const float* bk = (const float*)d_in[4];
    const float* wv = (const float*)d_in[5];
    const float* bv = (const float*)d_in[6];
    const float* wo = (const float*)d_in[7];
    const float* bo = (const float*)d_in[8];

    char* W = (char*)d_ws;
    u16* xhi = (u16*)(W);                 // [4096][1024]            8 MB
    u16* whi = (u16*)(W + 8388608);       // [4][1024][1024]         8 MB
    u16* qkv = (u16*)(W + 16777216);      // Q,K [32][2048][64]; V^T [32][64][2048]  24 MB
    u16* Obf = (u16*)(W + 41943040);      // [4096][1024] bf16       8 MB

    u16* Qp  = qkv;
    u16* Kp  = qkv + 4194304;
    u16* Vtp = qkv + 8388608;

    k_convx<<<4096, 256, 0, stream>>>(x, xhi);
    k_convw<<<dim3(16, 16, 4), 256, 0, stream>>>(wq, wk, wv, wo, whi);
    k_gemm<<<dim3(32, 8, 3), 256, 0, stream>>>(xhi, whi, bq, bk, bv, qkv, Vtp);
    k_attn<<<dim3(1024), 256, 0, stream>>>(Qp, Kp, Vtp, Obf);
    k_gemmO<<<dim3(64, 8), 256, 0, stream>>>(Obf, whi + (size_t)3 * EMB * EMB,
                                             bo, (float*)d_out);
}

// Round 21
// 111.544 us; speedup vs baseline: 1.1040x; 1.0341x over previous
//
#include <hip/hip_runtime.h>
#include <stdint.h>

typedef __attribute__((ext_vector_type(8))) short v8s;
typedef __attribute__((ext_vector_type(4))) short v4s;
typedef __attribute__((ext_vector_type(4))) float v4f;
typedef __attribute__((ext_vector_type(2))) unsigned v2u;
typedef unsigned short u16;

#define EMB 1024
#define TOKS 4096
#define NSEQ 2048
#define NH 16
#define HD 64

__device__ __forceinline__ u16 f2bf(float f) {
    unsigned u = __builtin_bit_cast(unsigned, f);
    u += 0x7fffu + ((u >> 16) & 1u);
    return (u16)(u >> 16);
}
__device__ __forceinline__ float bf2f(u16 h) {
    unsigned u = ((unsigned)h) << 16;
    return __builtin_bit_cast(float, u);
}
__device__ __forceinline__ float exp2_fast(float x) {
#if __has_builtin(__builtin_amdgcn_exp2f)
    return __builtin_amdgcn_exp2f(x);   // compiler-managed v_exp_f32 (trans hazards handled)
#else
    return exp2f(x);
#endif
}
// pack hi16(t0) -> low half, hi16(t1) -> high half (builtin perm; NO inline asm in exp chains)
__device__ __forceinline__ unsigned pack_hi16(unsigned t0, unsigned t1) {
#if __has_builtin(__builtin_amdgcn_perm)
    return __builtin_amdgcn_perm(t1, t0, 0x07060302u);  // [t1.b3,t1.b2,t0.b3,t0.b2]
#else
    return (t0 >> 16) | (t1 & 0xffff0000u);
#endif
}

__device__ __forceinline__ void gll16(const void* g, void* l) {
    __builtin_amdgcn_global_load_lds(
        (const __attribute__((address_space(1))) unsigned int*)g,
        (__attribute__((address_space(3))) unsigned int*)l, 16, 0, 0);
}

// ---------------- convert x -> bf16 hi-only [tok][1024] ----------------
__global__ void k_convx(const float* __restrict__ x, u16* __restrict__ xhi) {
    int i = (blockIdx.x * 256 + threadIdx.x) * 4;
    v4f v = *(const v4f*)(x + i);
    v4s h;
#pragma unroll
    for (int j = 0; j < 4; j++) h[j] = (short)f2bf(v[j]);
    *(v4s*)(xhi + i) = h;
}

// ---------------- transpose weights -> whi [z][out][1024] bf16 (all four) ----------------
__global__ void k_convw(const float* __restrict__ w0, const float* __restrict__ w1,
                        const float* __restrict__ w2, const float* __restrict__ w3,
                        u16* __restrict__ whi) {
    __shared__ float t[64][65];
    int z = blockIdx.z;
    const float* w = (z == 0) ? w0 : (z == 1) ? w1 : (z == 2) ? w2 : w3;
    int r0 = blockIdx.x * 64, c0 = blockIdx.y * 64;
    int tr = threadIdx.x >> 4, tc = (threadIdx.x & 15) * 4;
#pragma unroll
    for (int i = 0; i < 4; i++) {
        int row = tr + i * 16;
        v4f v = *(const v4f*)(w + (size_t)(r0 + row) * EMB + c0 + tc);
#pragma unroll
        for (int j = 0; j < 4; j++) t[row][tc + j] = v[j];
    }
    __syncthreads();
    u16* dz = whi + (size_t)z * EMB * EMB;
#pragma unroll
    for (int i = 0; i < 4; i++) {
        int orow = tr + i * 16;
        v4s h;
#pragma unroll
        for (int j = 0; j < 4; j++) h[j] = (short)f2bf(t[tc + j][orow]);
        *(v4s*)(dz + (size_t)(c0 + orow) * EMB + r0 + tc) = h;
    }
}

// ---------------- plain-bf16 GEMM K=1024 (m97 schedule): QKV projections ----------------
__global__ __launch_bounds__(256, 2) void k_gemm(
    const u16* __restrict__ A, const u16* __restrict__ B0,
    const float* __restrict__ b0, const float* __restrict__ b1, const float* __restrict__ b2,
    u16* __restrict__ outBF, u16* __restrict__ vT) {
    __shared__ u16 sA[8192], sB[8192];
    int z = blockIdx.z;
    const u16* B = B0 + (size_t)z * EMB * EMB;
    const float* bias = (z == 0) ? b0 : (z == 1) ? b1 : b2;
    int f = blockIdx.y * 32 + blockIdx.x;
    int fp = (f & 7) * 32 + (f >> 3);
    int m0 = (fp & 31) * 128, n0 = (fp >> 5) * 128;
    int tid = threadIdx.x, lane = tid & 63, w = tid >> 6;
    int wm = w >> 1, wn = w & 1;
    int lr = lane & 15, lk = lane >> 4;
    int srow8 = lane >> 3, kc8 = lane & 7;
    v4f z4 = {0.f, 0.f, 0.f, 0.f};
    v4f acc[4][4];
#pragma unroll
    for (int mi = 0; mi < 4; mi++)
#pragma unroll
        for (int ni = 0; ni < 4; ni++) acc[mi][ni] = z4;

    int c0 = (lk ^ (lr & 7)) * 8, c1 = ((4 + lk) ^ (lr & 7)) * 8;
    for (int kt = 0; kt < 16; ++kt) {
#pragma unroll
        for (int ii = 0; ii < 4; ii++) {
            int it = w * 4 + ii;
            int row = it * 8 + srow8;
            int kc = kc8 ^ (row & 7);
            gll16(&A[(size_t)(m0 + row) * EMB + kt * 64 + kc * 8], &sA[it * 512]);
            gll16(&B[(size_t)(n0 + row) * EMB + kt * 64 + kc * 8], &sB[it * 512]);
        }
        __syncthreads();
        v8s af[4][2], bf[4][2];
#pragma unroll
        for (int i = 0; i < 4; i++) {
            int ra = (wm * 64 + i * 16 + lr) * 64;
            af[i][0] = *(const v8s*)(&sA[ra + c0]);
            af[i][1] = *(const v8s*)(&sA[ra + c1]);
            int rb = (wn * 64 + i * 16 + lr) * 64;
            bf[i][0] = *(const v8s*)(&sB[rb + c0]);
            bf[i][1] = *(const v8s*)(&sB[rb + c1]);
        }
#pragma unroll
        for (int mi = 0; mi < 4; mi++)
#pragma unroll
            for (int ni = 0; ni < 4; ni++) {
                acc[mi][ni] = __builtin_amdgcn_mfma_f32_16x16x32_bf16(af[mi][0], bf[ni][0], acc[mi][ni], 0, 0, 0);
                acc[mi][ni] = __builtin_amdgcn_mfma_f32_16x16x32_bf16(af[mi][1], bf[ni][1], acc[mi][ni], 0, 0, 0);
            }
        __syncthreads();
    }

#pragma unroll
    for (int mi = 0; mi < 4; mi++) {
#pragma unroll
        for (int ni = 0; ni < 4; ni++) {
            int col = n0 + wn * 64 + ni * 16 + lr;
            float bv = bias[col];
            if (z == 2) {
                int h = col >> 6, d = col & 63;
                v4s pk;
#pragma unroll
                for (int r = 0; r < 4; r++) pk[r] = (short)f2bf(acc[mi][ni][r] + bv);
                int row = m0 + wm * 64 + mi * 16 + lk * 4;
                int bb = row >> 11, nn = row & 2047;
                *(v4s*)(&vT[((size_t)(bb * NH + h) * HD + d) * NSEQ + nn]) = pk;
            } else {
#pragma unroll
                for (int r = 0; r < 4; r++) {
                    int row = m0 + wm * 64 + mi * 16 + lk * 4 + r;
                    float val = acc[mi][ni][r] + bv;
                    if (z == 0) val *= 0.18033688011112042f;  // (1/8)*log2(e)
                    int bb = row >> 11, nn = row & 2047, h = col >> 6, d = col & 63;
                    size_t idx = (((size_t)(bb * NH + h)) * NSEQ + nn) * HD + d;
                    (outBF + (size_t)z * TOKS * EMB)[idx] = f2bf(val);
                }
            }
        }
    }
}

// ---------------- O-projection: 64x128 tile, K=1024 plain-bf16 (grid 512 = 2 blocks/CU) ----------------
__global__ __launch_bounds__(256, 2) void k_gemmO(
    const u16* __restrict__ A, const u16* __restrict__ B,
    const float* __restrict__ bias, float* __restrict__ outF) {
    __shared__ u16 sA[4096], sB[8192];
    int f = blockIdx.y * 64 + blockIdx.x;
    int fp = (f & 7) * 64 + (f >> 3);
    int m0 = (fp & 63) * 64, n0 = (fp >> 6) * 128;
    int tid = threadIdx.x, lane = tid & 63, w = tid >> 6;
    int wm = w >> 1, wn = w & 1;
    int lr = lane & 15, lk = lane >> 4;
    int srow8 = lane >> 3, kc8 = lane & 7;
    v4f z4 = {0.f, 0.f, 0.f, 0.f};
    v4f acc[2][4];
#pragma unroll
    for (int mi = 0; mi < 2; mi++)
#pragma unroll
        for (int ni = 0; ni < 4; ni++) acc[mi][ni] = z4;

    int c0 = (lk ^ (lr & 7)) * 8, c1 = ((4 + lk) ^ (lr & 7)) * 8;
    for (int kt = 0; kt < 16; ++kt) {
#pragma unroll
        for (int ii = 0; ii < 2; ii++) {
            int it = w * 2 + ii;
            int row = it * 8 + srow8;
            int kc = kc8 ^ (row & 7);
            gll16(&A[(size_t)(m0 + row) * EMB + kt * 64 + kc * 8], &sA[it * 512]);
        }
#pragma unroll
        for (int ii = 0; ii < 4; ii++) {
            int it = w * 4 + ii;
            int row = it * 8 + srow8;
            int kc = kc8 ^ (row & 7);
            gll16(&B[(size_t)(n0 + row) * EMB + kt * 64 + kc * 8], &sB[it * 512]);
        }
        __syncthreads();
        v8s af[2][2], bf[4][2];
#pragma unroll
        for (int i = 0; i < 2; i++) {
            int ra = (wm * 32 + i * 16 + lr) * 64;
            af[i][0] = *(const v8s*)(&sA[ra + c0]);
            af[i][1] = *(const v8s*)(&sA[ra + c1]);
        }
#pragma unroll
        for (int i = 0; i < 4; i++) {
            int rb = (wn * 64 + i * 16 + lr) * 64;
            bf[i][0] = *(const v8s*)(&sB[rb + c0]);
            bf[i][1] = *(const v8s*)(&sB[rb + c1]);
        }
#pragma unroll
        for (int mi = 0; mi < 2; mi++)
#pragma unroll
            for (int ni = 0; ni < 4; ni++) {
                acc[mi][ni] = __builtin_amdgcn_mfma_f32_16x16x32_bf16(af[mi][0], bf[ni][0], acc[mi][ni], 0, 0, 0);
                acc[mi][ni] = __builtin_amdgcn_mfma_f32_16x16x32_bf16(af[mi][1], bf[ni][1], acc[mi][ni], 0, 0, 0);
            }
        __syncthreads();
    }
#pragma unroll
    for (int mi = 0; mi < 2; mi++)
#pragma unroll
        for (int ni = 0; ni < 4; ni++) {
            int col = n0 + wn * 64 + ni * 16 + lr;
            float bv = bias[col];
#pragma unroll
            for (int r = 0; r < 4; r++) {
                int row = m0 + wm * 32 + mi * 16 + lk * 4 + r;
                outF[(size_t)row * EMB + col] = acc[mi][ni][r] + bv;
            }
        }
}

// ---------------- flash attention (R18): swapped QK^T, reg-Q, V^T global ----------------
// 4 waves x 64 q-rows, 64-key tiles, k-split K reads, trunc pack, single sP + 2 barriers/tile.
// LDS 24KB. sL aliased over sK (dead after last in-loop barrier).
__global__ __launch_bounds__(256, 4) void k_attn(
    const u16* __restrict__ Q, const u16* __restrict__ K, const u16* __restrict__ Vt,
    u16* __restrict__ O) {
    __shared__ u16 sK[2][4096];
    __shared__ u16 sP[4096];
    float* sL = (float*)&sK[0][0];   // alias: all sK reads precede the final in-loop barrier
    int tid = threadIdx.x, lane = tid & 63, w = tid >> 6;
    int lr = lane & 15, lk = lane >> 4;
    int bid = blockIdx.x;
    int qi = (bid >> 3) & 31;
    int bh = (bid & 7) | (((bid >> 8) & 3) << 3);  // bid%8 = XCD; 4 bh/XCD -> K,Vt L2-resident
    int q0 = qi * 64;

    const u16* Qb = Q + ((size_t)bh * NSEQ + q0) * HD;
    v8s qf[4][2];
#pragma unroll
    for (int qg = 0; qg < 4; qg++)
#pragma unroll
        for (int c = 0; c < 2; c++)
            qf[qg][c] = *(const v8s*)(Qb + (qg * 16 + lr) * HD + c * 32 + lk * 8);

    const u16* Kb = K + (size_t)bh * NSEQ * HD;
    const u16* Vb = Vt + ((size_t)bh * HD + w * 16 + lr) * NSEQ;  // this wave's d-row
    v4f z4 = {0.f, 0.f, 0.f, 0.f};
    v4f oacc[4] = {z4, z4, z4, z4};
    float l_part[4] = {0.f, 0.f, 0.f, 0.f};
    int srow8 = lane >> 3, kc8 = lane & 7;

    // prologue: stage K tile 0
#pragma unroll
    for (int ii = 0; ii < 2; ii++) {
        int it = w * 2 + ii;
        int row = it * 8 + srow8;
        int kc = kc8 ^ (row & 7);
        gll16(&Kb[(size_t)row * HD + kc * 8], &sK[0][it * 512]);
    }
    __syncthreads();

    int kread0 = (w * 16 + lr) * 64 + ((lk ^ (lr & 7)) * 8);
    int kread1 = (w * 16 + lr) * 64 + (((4 + lk) ^ (lr & 7)) * 8);
    int pwbase = (((w * 2 + (lk >> 1)) ^ (lr & 7)) << 2) + (lk & 1) * 2;

    for (int t = 0; t < 32; ++t) {
        int cur = t & 1;
        if (t < 31) {
#pragma unroll
            for (int ii = 0; ii < 2; ii++) {
                int it = w * 2 + ii;
                int row = it * 8 + srow8;
                int kc = kc8 ^ (row & 7);
                gll16(&Kb[(size_t)((t + 1) * 64 + row) * HD + kc * 8], &sK[cur ^ 1][it * 512]);
            }
        }
        v8s vb0 = *(const v8s*)(Vb + t * 64 + lk * 8);
        v8s vb1 = *(const v8s*)(Vb + t * 64 + 32 + lk * 8);

        v8s kf0 = *(const v8s*)(&sK[cur][kread0]);
        v8s kf1 = *(const v8s*)(&sK[cur][kread1]);
        v4f sacc[4];
#pragma unroll
        for (int qg = 0; qg < 4; qg++) {
            v4f a = z4;
            a = __builtin_amdgcn_mfma_f32_16x16x32_bf16(kf0, qf[qg][0], a, 0, 0, 0);
            a = __builtin_amdgcn_mfma_f32_16x16x32_bf16(kf1, qf[qg][1], a, 0, 0, 0);
            sacc[qg] = a;
        }
        // p = exp2(s); f32 l accumulate; TRUNCATION pack (softmax ratio cancels the uniform bias)
        float pv[4][4];
#pragma unroll
        for (int qg = 0; qg < 4; qg++) {
            pv[qg][0] = exp2_fast(sacc[qg][0]);
            pv[qg][1] = exp2_fast(sacc[qg][1]);
            pv[qg][2] = exp2_fast(sacc[qg][2]);
            pv[qg][3] = exp2_fast(sacc[qg][3]);
            l_part[qg] += (pv[qg][0] + pv[qg][1]) + (pv[qg][2] + pv[qg][3]);
        }
        __syncthreads();   // barrier A: prev tile's sP readers are done
#pragma unroll
        for (int qg = 0; qg < 4; qg++) {
            unsigned pk0 = pack_hi16(__builtin_bit_cast(unsigned, pv[qg][0]),
                                     __builtin_bit_cast(unsigned, pv[qg][1]));
            unsigned pk1 = pack_hi16(__builtin_bit_cast(unsigned, pv[qg][2]),
                                     __builtin_bit_cast(unsigned, pv[qg][3]));
            int q = qg * 16 + lr;
            v2u pk = {pk0, pk1};
            *(v2u*)(&sP[(q * 32 + pwbase) * 2]) = pk;
        }
        __syncthreads();   // barrier B: sP visible; drains this tile's gll16 (sK[cur^1] ready)
#pragma unroll
        for (int qg = 0; qg < 4; qg++) {
            int q = qg * 16 + lr;
            v8s pf0 = *(const v8s*)(&sP[(q * 32 + ((lk ^ (lr & 7)) << 2)) * 2]);
            v8s pf1 = *(const v8s*)(&sP[(q * 32 + (((4 + lk) ^ (lr & 7)) << 2)) * 2]);
            oacc[qg] = __builtin_amdgcn_mfma_f32_16x16x32_bf16(pf0, vb0, oacc[qg], 0, 0, 0);
            oacc[qg] = __builtin_amdgcn_mfma_f32_16x16x32_bf16(pf1, vb1, oacc[qg], 0, 0, 0);
        }
    }
    // deferred l: reduce across lk groups, then across waves via sL (aliased over dead sK)
#pragma unroll
    for (int qg = 0; qg < 4; qg++) {
        l_part[qg] += __shfl_xor(l_part[qg], 16);
        l_part[qg] += __shfl_xor(l_part[qg], 32);
    }
    __syncthreads();   // all PV reads of sP done; sK fully dead -> safe to write sL alias
    if (lk == 0) {
#pragma unroll
        for (int qg = 0; qg < 4; qg++) sL[(qg * 16 + lr) * 4 + w] = l_part[qg];
    }
    __syncthreads();
    int bb = bh >> 4, h = bh & 15;
    int dcol = h * 64 + w * 16 + lr;
#pragma unroll
    for (int qg = 0; qg < 4; qg++) {
#pragma unroll
        for (int r = 0; r < 4; r++) {
            int qq = qg * 16 + lk * 4 + r;
            v4f lv = *(const v4f*)(&sL[qq * 4]);
            float inv = 1.f / ((lv[0] + lv[1]) + (lv[2] + lv[3]));
            O[(size_t)(bb * NSEQ + q0 + qq) * EMB + dcol] = f2bf(oacc[qg][r] * inv);
        }
    }
}

extern "C" void kernel_launch(void* const* d_in, const int* in_sizes, int n_in,
                              void* d_out, int out_size, void* d_ws, size_t ws_size,
                              hipStream_t stream) {
    const float* x  = (const float*)d_in[0];
    const float* wq = (const float*)d_in[1];
    const float* bq = (const float*)d_in[2];
    const float* wk = (const float*)d_in[3];
    const float* bk = (const float*)d_in[4];
    const float* wv = (const float*)d_in[5];
    const float* bv = (const float*)d_in[6];
    const float* wo = (const float*)d_in[7];
    const float* bo = (const float*)d_in[8];

    char* W = (char*)d_ws;
    u16* xhi = (u16*)(W);                 // [4096][1024]            8 MB
    u16* whi = (u16*)(W + 8388608);       // [4][1024][1024]         8 MB
    u16* qkv = (u16*)(W + 16777216);      // Q,K [32][2048][64]; V^T [32][64][2048]  24 MB
    u16* Obf = (u16*)(W + 41943040);      // [4096][1024] bf16       8 MB

    u16* Qp  = qkv;
    u16* Kp  = qkv + 4194304;
    u16* Vtp = qkv + 8388608;

    k_convx<<<4096, 256, 0, stream>>>(x, xhi);
    k_convw<<<dim3(16, 16, 4), 256, 0, stream>>>(wq, wk, wv, wo, whi);
    k_gemm<<<dim3(32, 8, 3), 256, 0, stream>>>(xhi, whi, bq, bk, bv, qkv, Vtp);
    k_attn<<<dim3(1024), 256, 0, stream>>>(Qp, Kp, Vtp, Obf);
    k_gemmO<<<dim3(64, 8), 256, 0, stream>>>(Obf, whi + (size_t)3 * EMB * EMB,
                                             bo, (float*)d_out);
}